// Round 7
// baseline (329.780 us; speedup 1.0000x reference)
//
#include <hip/hip_runtime.h>
#include <math.h>

#define R2 2500.0f
#define EPSF 1e-8f

constexpr int H   = 256;   // feature dim (fixed by problem)
constexpr int HH  = 128;   // hidden dim
constexpr int NB  = 8;     // col-buckets per row (bucket = col>>11 -> 2048 nodes = 2MB of x)
constexpr int BSH = 11;    // bucket shift
constexpr int RPW = 4;     // rows per wave in k_fvar

// ---------------- K1: degree count per (row, bucket) ----------------
__global__ void k_degree(const int* __restrict__ row, const int* __restrict__ col,
                         int* __restrict__ deg4, int E) {
    int e = blockIdx.x * blockDim.x + threadIdx.x;
    if (e < E) atomicAdd(&deg4[row[e] * NB + (col[e] >> BSH)], 1);
}

// ---------------- K2: parallel exclusive scan over M=N*NB ----------------
__global__ void __launch_bounds__(256) k_bsum(const int* __restrict__ deg4,
                                              int* __restrict__ bsum) {
    int t = threadIdx.x;
    int4 v = ((const int4*)deg4)[blockIdx.x * 256 + t];
    int sum = v.x + v.y + v.z + v.w;
#pragma unroll
    for (int off = 32; off > 0; off >>= 1) sum += __shfl_xor(sum, off, 64);
    __shared__ int sw[4];
    if ((t & 63) == 0) sw[t >> 6] = sum;
    __syncthreads();
    if (t == 0) bsum[blockIdx.x] = sw[0] + sw[1] + sw[2] + sw[3];
}

__global__ void k_bscan(const int* __restrict__ bsum, int* __restrict__ boff) {
    __shared__ int s[128];
    int t = threadIdx.x;
    s[t] = bsum[t];
    __syncthreads();
    for (int off = 1; off < 128; off <<= 1) {
        int v = s[t];
        int add = (t >= off) ? s[t - off] : 0;
        __syncthreads();
        s[t] = v + add;
        __syncthreads();
    }
    boff[t] = (t > 0) ? s[t - 1] : 0;
}

__global__ void __launch_bounds__(256) k_scat(const int* __restrict__ deg4,
                                              const int* __restrict__ boff,
                                              int* __restrict__ rp4,
                                              int* __restrict__ cur4, int M) {
    int t = threadIdx.x, blk = blockIdx.x;
    int lane = t & 63, w = t >> 6;
    int4 v = ((const int4*)deg4)[blk * 256 + t];
    int tsum = v.x + v.y + v.z + v.w;
    int incl = tsum;
#pragma unroll
    for (int off = 1; off < 64; off <<= 1) {
        int n = __shfl_up(incl, off, 64);
        if (lane >= off) incl += n;
    }
    __shared__ int wsum[4];
    if (lane == 63) wsum[w] = incl;
    __syncthreads();
    int woff = 0;
#pragma unroll
    for (int k = 0; k < 4; k++) woff += (k < w) ? wsum[k] : 0;
    int excl = boff[blk] + woff + (incl - tsum);
    int4 r;
    r.x = excl;
    r.y = excl + v.x;
    r.z = excl + v.x + v.y;
    r.w = excl + v.x + v.y + v.z;
    ((int4*)rp4)[blk * 256 + t]  = r;
    ((int4*)cur4)[blk * 256 + t] = r;
    if (blk == gridDim.x - 1 && t == 255) rp4[M] = excl + tsum;
}

// ---------------- K3: fill bucket-sorted CSR ----------------
__global__ void k_fill(const int* __restrict__ row, const int* __restrict__ col,
                       int* __restrict__ cur4, int* __restrict__ cols, int E) {
    int e = blockIdx.x * blockDim.x + threadIdx.x;
    if (e < E) {
        int r = row[e], c = col[e];
        int p = atomicAdd(&cur4[r * NB + (c >> BSH)], 1);
        cols[p] = c;
    }
}

// ---------------- K4: spatial density via 20x20 cell grid ----------------
__global__ void k_cellcnt(const float* __restrict__ coords, int* __restrict__ cellcnt, int N) {
    int t = blockIdx.x * 256 + threadIdx.x;
    float2 c = ((const float2*)coords)[t];
    int cx = (int)(c.x * 0.02f); if (cx > 19) cx = 19;
    int cy = (int)(c.y * 0.02f); if (cy > 19) cy = 19;
    atomicAdd(&cellcnt[cy * 20 + cx], 1);
}

__global__ void k_cellscan(const int* __restrict__ cellcnt, int* __restrict__ cellstart,
                           int* __restrict__ cellcur) {
    __shared__ int s[512];
    int t = threadIdx.x;
    s[t] = (t < 400) ? cellcnt[t] : 0;
    __syncthreads();
    for (int off = 1; off < 512; off <<= 1) {
        int v = s[t];
        int add = (t >= off) ? s[t - off] : 0;
        __syncthreads();
        s[t] = v + add;
        __syncthreads();
    }
    if (t < 400) {
        int excl = (t > 0) ? s[t - 1] : 0;
        cellstart[t] = excl;
        cellcur[t]   = excl;
    }
    if (t == 400) cellstart[400] = s[399];
}

__global__ void k_cellfill(const float* __restrict__ coords, int* __restrict__ cellcur,
                           float4* __restrict__ pts, int N) {
    int t = blockIdx.x * 256 + threadIdx.x;
    float2 c = ((const float2*)coords)[t];
    int cx = (int)(c.x * 0.02f); if (cx > 19) cx = 19;
    int cy = (int)(c.y * 0.02f); if (cy > 19) cy = 19;
    int p = atomicAdd(&cellcur[cy * 20 + cx], 1);
    pts[p] = make_float4(c.x, c.y, c.x * c.x + c.y * c.y, __int_as_float(t));
}

__global__ void __launch_bounds__(256) k_dgrid(
    const float4* __restrict__ pts, const int* __restrict__ cellstart,
    int* __restrict__ dens, int N) {
    int wave = threadIdx.x >> 6;
    int lane = threadIdx.x & 63;
    int t = blockIdx.x * 4 + wave;          // one wave per point
    float4 p = pts[t];
    int cx = (int)(p.x * 0.02f); if (cx > 19) cx = 19;
    int cy = (int)(p.y * 0.02f); if (cy > 19) cy = 19;
    int x0 = cx - 2; if (x0 < 0) x0 = 0;
    int x1 = cx + 2; if (x1 > 19) x1 = 19;
    int y0 = cy - 2; if (y0 < 0) y0 = 0;
    int y1 = cy + 2; if (y1 > 19) y1 = 19;
    int cnt = 0;
    for (int yy = y0; yy <= y1; yy++) {
        int rowb = yy * 20;
        int s = cellstart[rowb + x0];        // wave-uniform
        int e = cellstart[rowb + x1 + 1];    // cells in a row contiguous in pts
        for (int q = s + lane; q < e; q += 64) {   // coalesced lane-strided
            float4 pq = pts[q];
            float dot = p.x * pq.x + p.y * pq.y;
            float d2 = (p.z + pq.z) - 2.0f * dot;
            cnt += (d2 <= R2) ? 1 : 0;
        }
    }
#pragma unroll
    for (int off = 32; off > 0; off >>= 1) cnt += __shfl_xor(cnt, off, 64);
    if (lane == 0) dens[__float_as_int(p.w)] = cnt;
}

// ---------------- K5: fvar — bucket-major sweep, register ping-pong gather ----
// vs R6: (1) all 33 segment boundaries for the wave's 4 rows preloaded in ONE
// coalesced load -> per-segment s/e are shfl's; (2) cols preloaded into 4
// VGPRs (uniform-load fallback past 256, ~never) -> per-slot index is pure
// VALU; (3) gather into REGISTERS: two 8-slot float4 buffers, ping-pong over
// the statically-unrolled r loop, so the compiler's dataflow vmcnt gives a
// counted wait (segment q+1's 8 loads stay in flight while q is accumulated —
// never drains to 0). Padded slots load a lane-invariant 16B dummy (one 64B
// line, ~free) and are masked by exact *1.0/*0.0 FMA. m>8 tails (~2% of
// segments, Poisson(4)) take a rare serial path. No LDS; launch_bounds(256,4)
// caps VGPRs at 128 so the 1024-block grid stays 4/CU all-resident (the
// phase-synced bucket sweep that got FETCH 207->75MB needs co-residency).
__global__ void __launch_bounds__(256, 4) k_fvar(
    const float* __restrict__ x, const int* __restrict__ rp4,
    const int* __restrict__ cols, float* __restrict__ fvar, int N) {
    int wave = threadIdx.x >> 6;
    int lane = threadIdx.x & 63;
    int i0 = (blockIdx.x * 4 + wave) * RPW;
    const float4* xb = (const float4*)x;   // 64 float4 per row

    // 33 segment boundaries (rows i0..i0+3 x 8 buckets) in lanes 0..32
    int bnd = rp4[i0 * NB + (lane < 32 ? lane : 32)];
    int S = __shfl(bnd, 0, 64);
    int T = __shfl(bnd, 32, 64);

    // preload up to 256 cols into 4 regs (clamped loads; garbage never used)
    int tc = T - 1; if (tc < S) tc = S;
    int pp = S + lane;
    int cr0 = cols[pp < T ? pp : tc]; pp += 64;
    int cr1 = cols[pp < T ? pp : tc]; pp += 64;
    int cr2 = cols[pp < T ? pp : tc]; pp += 64;
    int cr3 = cols[pp < T ? pp : tc];

    // broadcast col at absolute position pos (pos is wave-uniform)
    auto colAt = [&](int pos) -> int {
        int q = pos - S;
        if (q < 256) {
            int w = q >> 6;
            int src = (w == 0) ? cr0 : (w == 1) ? cr1 : (w == 2) ? cr2 : cr3;
            return __shfl(src, q & 63, 64);
        }
        return cols[pos];   // >256 edges across 4 rows: essentially never
    };

    float4 acc0 = make_float4(0.f, 0.f, 0.f, 0.f);
    float4 acc1 = make_float4(0.f, 0.f, 0.f, 0.f);
    float4 acc2 = make_float4(0.f, 0.f, 0.f, 0.f);
    float4 acc3 = make_float4(0.f, 0.f, 0.f, 0.f);
    float4 g[8], h[8];
    int pm = 0, ps = 0, cm, cs;

#define ISSUE(RR, BUF)                                                  \
    {                                                                   \
        int s_ = __shfl(bnd, (RR) * NB + b, 64);                        \
        int e_ = __shfl(bnd, (RR) * NB + b + 1, 64);                    \
        int m_ = e_ - s_;                                               \
        _Pragma("unroll")                                               \
        for (int k = 0; k < 8; k++) {                                   \
            size_t off_ = 0;   /* lane-invariant 16B dummy */           \
            if (k < m_) off_ = (size_t)colAt(s_ + k) * 64 + lane;       \
            BUF[k] = xb[off_];                                          \
        }                                                               \
        cm = m_; cs = s_;                                               \
    }

#define ACCP(ACCR, BUF)                                                 \
    {                                                                   \
        _Pragma("unroll")                                               \
        for (int k = 0; k < 8; k++) {                                   \
            float w_ = (k < pm) ? 1.0f : 0.0f;                          \
            ACCR.x += BUF[k].x * w_; ACCR.y += BUF[k].y * w_;           \
            ACCR.z += BUF[k].z * w_; ACCR.w += BUF[k].w * w_;           \
        }                                                               \
        if (pm > 8) {                                                   \
            for (int pq = ps + 8; pq < ps + pm; pq++) {                 \
                float4 v_ = xb[(size_t)colAt(pq) * 64 + lane];          \
                ACCR.x += v_.x; ACCR.y += v_.y;                         \
                ACCR.z += v_.z; ACCR.w += v_.w;                         \
            }                                                           \
        }                                                               \
    }

    for (int b = 0; b < NB; b++) {
        ISSUE(0, g);
        if (b > 0) { ACCP(acc3, h); }
        pm = cm; ps = cs;
        ISSUE(1, h);
        ACCP(acc0, g);
        pm = cm; ps = cs;
        ISSUE(2, g);
        ACCP(acc1, h);
        pm = cm; ps = cs;
        ISSUE(3, h);
        ACCP(acc2, g);
        pm = cm; ps = cs;
    }
    ACCP(acc3, h);   // last segment (b=7, r=3)

#undef ISSUE
#undef ACCP

#define FIN(RR, ACCR)                                                   \
    {                                                                   \
        int i = i0 + (RR);                                              \
        float cnt = fmaxf((float)(__shfl(bnd, (RR) * NB + NB, 64) -     \
                                  __shfl(bnd, (RR) * NB, 64)), 1.0f);   \
        float4 xi = xb[(size_t)i * 64 + lane];                          \
        float dx = xi.x - ACCR.x / cnt;                                 \
        float dy = xi.y - ACCR.y / cnt;                                 \
        float dz = xi.z - ACCR.z / cnt;                                 \
        float dw = xi.w - ACCR.w / cnt;                                 \
        float ss = dx * dx + dy * dy + dz * dz + dw * dw;               \
        _Pragma("unroll")                                               \
        for (int off = 32; off > 0; off >>= 1) ss += __shfl_xor(ss, off, 64); \
        if (lane == 0) fvar[i] = sqrtf(ss);                             \
    }

    FIN(0, acc0);
    FIN(1, acc1);
    FIN(2, acc2);
    FIN(3, acc3);
#undef FIN
}

// ---------------- K5b: maxima reduction (deg, dens, fvar) ----------------
__global__ void __launch_bounds__(256) k_scal(
    const int* __restrict__ rp4, const int* __restrict__ dens,
    const float* __restrict__ fvar, int* __restrict__ scal, int N) {
    __shared__ int sd[4], sn[4];
    __shared__ float sf[4];
    int t = threadIdx.x;
    int g = blockIdx.x * 256 + t;
    int stride = 256 * gridDim.x;
    int md = 0, mn = 0;
    float mf = 0.f;
    for (int i = g; i < N; i += stride) {
        md = max(md, rp4[(i + 1) * NB] - rp4[i * NB]);
        mn = max(mn, dens[i]);
        mf = fmaxf(mf, fvar[i]);
    }
#pragma unroll
    for (int off = 32; off > 0; off >>= 1) {
        md = max(md, __shfl_xor(md, off, 64));
        mn = max(mn, __shfl_xor(mn, off, 64));
        mf = fmaxf(mf, __shfl_xor(mf, off, 64));
    }
    int w = t >> 6, l = t & 63;
    if (l == 0) { sd[w] = md; sn[w] = mn; sf[w] = mf; }
    __syncthreads();
    if (t == 0) {
#pragma unroll
        for (int k = 1; k < 4; k++) {
            md = max(md, sd[k]);
            mn = max(mn, sn[k]);
            mf = fmaxf(mf, sf[k]);
        }
        atomicMax(&scal[0], md);
        atomicMax(&scal[1], mn);
        atomicMax(&scal[2], __float_as_int(mf));   // nonneg float: int-max ok
    }
}

// ---------------- K6: tiny MLP ----------------
__global__ void __launch_bounds__(256) k_mlp(
    const float* __restrict__ w1, const float* __restrict__ b1,
    const float* __restrict__ w2, const float* __restrict__ b2,
    const int* __restrict__ rp4, const int* __restrict__ dens,
    const float* __restrict__ fvar, const int* __restrict__ scal,
    float* __restrict__ out, int N) {
    __shared__ float sh_h[HH];
    int j = threadIdx.x;
    float wv[HH];
#pragma unroll
    for (int l = 0; l < HH; l++) wv[l] = w2[l * H + j];
    float bj = b2[j];
    float maxdeg  = (float)scal[0] + EPSF;
    float maxdens = (float)(scal[1] - 1) + EPSF;
    float maxfv   = __int_as_float(scal[2]) + EPSF;
    float w1a = 0.f, w1b = 0.f, w1c = 0.f, b1j = 0.f;
    if (j < HH) { w1a = w1[j]; w1b = w1[HH + j]; w1c = w1[2 * HH + j]; b1j = b1[j]; }
    for (int i = blockIdx.x; i < N; i += gridDim.x) {
        float f0 = (float)(rp4[(i + 1) * NB] - rp4[i * NB]) / maxdeg;
        float f1 = (float)(dens[i] - 1) / maxdens;
        float f2 = fvar[i] / maxfv;
        if (j < HH) {
            float h = f0 * w1a + f1 * w1b + f2 * w1c + b1j;
            sh_h[j] = fmaxf(h, 0.0f);
        }
        __syncthreads();
        float acc = bj;
#pragma unroll
        for (int l = 0; l < HH; l++) acc = fmaf(sh_h[l], wv[l], acc);
        out[(size_t)i * H + j] = acc;
        __syncthreads();
    }
}

extern "C" void kernel_launch(void* const* d_in, const int* in_sizes, int n_in,
                              void* d_out, int out_size, void* d_ws, size_t ws_size,
                              hipStream_t stream) {
    const float* x      = (const float*)d_in[0];
    const int*   ei     = (const int*)d_in[1];
    const float* coords = (const float*)d_in[2];
    const float* w1     = (const float*)d_in[3];
    const float* b1     = (const float*)d_in[4];
    const float* w2     = (const float*)d_in[5];
    const float* b2     = (const float*)d_in[6];
    float* out = (float*)d_out;

    const int N = in_sizes[2] / 2;   // 16384
    const int E = in_sizes[1] / 2;   // 524288
    const int M = N * NB;            // 131072
    const int NBLK = M / 1024;       // 128 scan blocks
    const int* row = ei;
    const int* col = ei + E;

    // workspace layout (int32 elements; int4/float4 arrays 16B-aligned)
    int* ws        = (int*)d_ws;
    int* scal      = ws;                       // [4]     zeroed
    int* deg4      = ws + 4;                   // [M]     zeroed  (16B-aligned)
    int* cellcnt   = ws + 4 + M;               // [404]   zeroed  (400 used)
    int* rp4       = ws + 408 + M;             // [M+4]           (16B-aligned)
    int* cur4      = rp4 + M + 4;              // [M]             (16B-aligned)
    int* cellstart = cur4 + M;                 // [404]   (401 used)
    int* cellcur   = cellstart + 404;          // [400]
    int* dens_cnt  = cellcur + 400;            // [N]
    float* fvarp   = (float*)(dens_cnt + N);   // [N]
    int* bsum      = dens_cnt + 2 * N;         // [128]
    int* boff      = bsum + 128;               // [128]
    int* cols      = boff + 128;               // [E]
    float4* pts    = (float4*)(cols + E);      // [N]  (16B-aligned)

    hipMemsetAsync(ws, 0, (size_t)(408 + M) * sizeof(int), stream);

    int eb = (E + 255) / 256;
    k_degree<<<eb, 256, 0, stream>>>(row, col, deg4, E);
    k_bsum<<<NBLK, 256, 0, stream>>>(deg4, bsum);
    k_bscan<<<1, NBLK, 0, stream>>>(bsum, boff);
    k_scat<<<NBLK, 256, 0, stream>>>(deg4, boff, rp4, cur4, M);
    k_fill<<<eb, 256, 0, stream>>>(row, col, cur4, cols, E);

    k_cellcnt<<<N / 256, 256, 0, stream>>>(coords, cellcnt, N);
    k_cellscan<<<1, 512, 0, stream>>>(cellcnt, cellstart, cellcur);
    k_cellfill<<<N / 256, 256, 0, stream>>>(coords, cellcur, pts, N);
    k_dgrid<<<N / 4, 256, 0, stream>>>(pts, cellstart, dens_cnt, N);

    k_fvar<<<N / (4 * RPW), 256, 0, stream>>>(x, rp4, cols, fvarp, N);

    k_scal<<<64, 256, 0, stream>>>(rp4, dens_cnt, fvarp, scal, N);

    k_mlp<<<1024, 256, 0, stream>>>(w1, b1, w2, b2, rp4, dens_cnt, fvarp, scal,
                                    out, N);
}

// Round 8
// 255.631 us; speedup vs baseline: 1.2901x; 1.2901x over previous
//
#include <hip/hip_runtime.h>
#include <math.h>

#define R2 2500.0f
#define EPSF 1e-8f

constexpr int H   = 256;   // feature dim (fixed by problem)
constexpr int HH  = 128;   // hidden dim
constexpr int NB  = 8;     // col-buckets per row (bucket = col>>11 -> 2MB of x)
constexpr int BSH = 11;    // bucket shift
constexpr int RPW = 4;     // rows per wave in k_fvar

// ---------------- K1f: degree count + cell count (fused) ----------------
__global__ void __launch_bounds__(256) k_degcell(
    const int* __restrict__ row, const int* __restrict__ col,
    int* __restrict__ deg4, const float* __restrict__ coords,
    int* __restrict__ cellcnt, int E, int EB, int N) {
    if ((int)blockIdx.x < EB) {
        int e = blockIdx.x * 256 + threadIdx.x;
        if (e < E) atomicAdd(&deg4[row[e] * NB + (col[e] >> BSH)], 1);
    } else {
        int t = ((int)blockIdx.x - EB) * 256 + threadIdx.x;
        if (t < N) {
            float2 c = ((const float2*)coords)[t];
            int cx = (int)(c.x * 0.02f); if (cx > 19) cx = 19;
            int cy = (int)(c.y * 0.02f); if (cy > 19) cy = 19;
            atomicAdd(&cellcnt[cy * 20 + cx], 1);
        }
    }
}

// ---------------- K2a: per-block sums over M (128 blocks) ----------------
__global__ void __launch_bounds__(256) k_bsum(const int* __restrict__ deg4,
                                              int* __restrict__ bsum) {
    int t = threadIdx.x;
    int4 v = ((const int4*)deg4)[blockIdx.x * 256 + t];
    int sum = v.x + v.y + v.z + v.w;
#pragma unroll
    for (int off = 32; off > 0; off >>= 1) sum += __shfl_xor(sum, off, 64);
    __shared__ int sw[4];
    if ((t & 63) == 0) sw[t >> 6] = sum;
    __syncthreads();
    if (t == 0) bsum[blockIdx.x] = sw[0] + sw[1] + sw[2] + sw[3];
}

// ---------------- K2f: scat (with internal bsum prefix) + cellscan --------
// blocks 0..127: scatter scan of deg4 -> rp4,cur4 (each block re-scans the
// 128 bsums in LDS: 512B, L2-hot, ~free; kills the serial k_bscan launch).
// block 128: cell scan (400 cells).
__global__ void __launch_bounds__(512) k_scatcell(
    const int* __restrict__ deg4, const int* __restrict__ bsum,
    int* __restrict__ rp4, int* __restrict__ cur4, int M,
    const int* __restrict__ cellcnt, int* __restrict__ cellstart,
    int* __restrict__ cellcur) {
    __shared__ int s[512];
    int t = threadIdx.x;
    int blk = blockIdx.x;
    if (blk < gridDim.x - 1) {
        // inclusive scan of the 128 block sums
        s[t] = (t < 128) ? bsum[t] : 0;
        __syncthreads();
        for (int off = 1; off < 128; off <<= 1) {
            int v = (t < 128) ? s[t] : 0;
            int add = (t >= off && t < 128) ? s[t - off] : 0;
            __syncthreads();
            if (t < 128) s[t] = v + add;
            __syncthreads();
        }
        int boff = (blk > 0) ? s[blk - 1] : 0;
        if (t < 256) {
            int lane = t & 63, w = t >> 6;
            int4 v = ((const int4*)deg4)[blk * 256 + t];
            int tsum = v.x + v.y + v.z + v.w;
            int incl = tsum;
#pragma unroll
            for (int off = 1; off < 64; off <<= 1) {
                int n = __shfl_up(incl, off, 64);
                if (lane >= off) incl += n;
            }
            __shared__ int wsum[4];
            if (lane == 63) wsum[w] = incl;
            __syncthreads();
            int woff = 0;
#pragma unroll
            for (int k = 0; k < 4; k++) woff += (k < w) ? wsum[k] : 0;
            int excl = boff + woff + (incl - tsum);
            int4 r;
            r.x = excl;
            r.y = excl + v.x;
            r.z = excl + v.x + v.y;
            r.w = excl + v.x + v.y + v.z;
            ((int4*)rp4)[blk * 256 + t]  = r;
            ((int4*)cur4)[blk * 256 + t] = r;
            if (blk == 127 && t == 255) rp4[M] = excl + tsum;
        }
    } else {
        // cell scan
        s[t] = (t < 400) ? cellcnt[t] : 0;
        __syncthreads();
        for (int off = 1; off < 512; off <<= 1) {
            int v = s[t];
            int add = (t >= off) ? s[t - off] : 0;
            __syncthreads();
            s[t] = v + add;
            __syncthreads();
        }
        if (t < 400) {
            int excl = (t > 0) ? s[t - 1] : 0;
            cellstart[t] = excl;
            cellcur[t]   = excl;
        }
        if (t == 400) cellstart[400] = s[399];
    }
}

// ---------------- K3f: CSR fill + cell fill (fused) ----------------
__global__ void __launch_bounds__(256) k_fillcell(
    const int* __restrict__ row, const int* __restrict__ col,
    int* __restrict__ cur4, int* __restrict__ cols,
    const float* __restrict__ coords, int* __restrict__ cellcur,
    float4* __restrict__ pts, int E, int EB, int N) {
    if ((int)blockIdx.x < EB) {
        int e = blockIdx.x * 256 + threadIdx.x;
        if (e < E) {
            int r = row[e], c = col[e];
            int p = atomicAdd(&cur4[r * NB + (c >> BSH)], 1);
            cols[p] = c;
        }
    } else {
        int t = ((int)blockIdx.x - EB) * 256 + threadIdx.x;
        if (t < N) {
            float2 c = ((const float2*)coords)[t];
            int cx = (int)(c.x * 0.02f); if (cx > 19) cx = 19;
            int cy = (int)(c.y * 0.02f); if (cy > 19) cy = 19;
            int p = atomicAdd(&cellcur[cy * 20 + cx], 1);
            pts[p] = make_float4(c.x, c.y, c.x * c.x + c.y * c.y, __int_as_float(t));
        }
    }
}

// ---------------- K4: density, one wave per point (R6-proven) ----------------
__global__ void __launch_bounds__(256) k_dgrid(
    const float4* __restrict__ pts, const int* __restrict__ cellstart,
    int* __restrict__ dens, int N) {
    int wave = threadIdx.x >> 6;
    int lane = threadIdx.x & 63;
    int t = blockIdx.x * 4 + wave;
    float4 p = pts[t];
    int cx = (int)(p.x * 0.02f); if (cx > 19) cx = 19;
    int cy = (int)(p.y * 0.02f); if (cy > 19) cy = 19;
    int x0 = cx - 2; if (x0 < 0) x0 = 0;
    int x1 = cx + 2; if (x1 > 19) x1 = 19;
    int y0 = cy - 2; if (y0 < 0) y0 = 0;
    int y1 = cy + 2; if (y1 > 19) y1 = 19;
    int cnt = 0;
    for (int yy = y0; yy <= y1; yy++) {
        int rowb = yy * 20;
        int s = cellstart[rowb + x0];
        int e = cellstart[rowb + x1 + 1];
        for (int q = s + lane; q < e; q += 64) {
            float4 pq = pts[q];
            float dot = p.x * pq.x + p.y * pq.y;
            float d2 = (p.z + pq.z) - 2.0f * dot;
            cnt += (d2 <= R2) ? 1 : 0;
        }
    }
#pragma unroll
    for (int off = 32; off > 0; off >>= 1) cnt += __shfl_xor(cnt, off, 64);
    if (lane == 0) dens[__float_as_int(p.w)] = cnt;
}

// ---------------- K5: fvar — bucket sweep, ROW-PACKED LDS gather ----------
// Gather mechanism = R6's proven global_load_lds -> 8 LDS slots -> drain ->
// accumulate (no register arrays: R7's reg ping-pong was demoted to LDS/
// scratch by the compiler — 1.1M bank conflicts, 7MB scratch writes).
// NEW vs R6: per bucket, the wave's 4 row-segments (avg 4 edges each) are
// PACKED into a single flat list (avg 16) and consumed in shared 8-slot
// batches; each slot demuxes to its row's accumulator via exact *1/*0 FMA.
// Drains per wave: 32 -> ~18. Per-acc summation order unchanged vs R6.
__global__ void __launch_bounds__(256) k_fvar(
    const float* __restrict__ x, const int* __restrict__ rp4,
    const int* __restrict__ cols, float* __restrict__ fvar, int N) {
    __shared__ float4 lds[4][8][64];   // 4 waves x 8 slots x 1KB = 32KB
    int wave = threadIdx.x >> 6;
    int lane = threadIdx.x & 63;
    int i0 = (blockIdx.x * 4 + wave) * RPW;
    const float4* xb = (const float4*)x;   // 64 float4 per row

    // 33 segment boundaries (rows i0..i0+3 x 8 buckets) in lanes 0..32
    int bnd = rp4[i0 * NB + (lane < 32 ? lane : 32)];

    float4 acc0 = make_float4(0.f, 0.f, 0.f, 0.f);
    float4 acc1 = make_float4(0.f, 0.f, 0.f, 0.f);
    float4 acc2 = make_float4(0.f, 0.f, 0.f, 0.f);
    float4 acc3 = make_float4(0.f, 0.f, 0.f, 0.f);

    for (int b = 0; b < NB; b++) {
        int s0 = __shfl(bnd, b, 64),      e0 = __shfl(bnd, b + 1, 64);
        int s1 = __shfl(bnd, 8 + b, 64),  e1 = __shfl(bnd, 9 + b, 64);
        int s2 = __shfl(bnd, 16 + b, 64), e2 = __shfl(bnd, 17 + b, 64);
        int s3 = __shfl(bnd, 24 + b, 64), e3 = __shfl(bnd, 25 + b, 64);
        int m0 = e0 - s0, m1 = e1 - s1, m2 = e2 - s2;
        int c1 = m0, c2 = m0 + m1, c3 = m0 + m1 + m2;
        int mt = c3 + (e3 - s3);
        if (mt == 0) continue;

        // lane j holds (row, col) of flat element j (j < mt; else clamp)
        int j = lane;
        int rowj = (j >= c1) + (j >= c2) + (j >= c3);
        int base = (rowj == 0) ? s0 : (rowj == 1) ? (s1 - c1)
                 : (rowj == 2) ? (s2 - c2) : (s3 - c3);
        int pos = base + j;
        if (j >= mt) pos = s0;          // s0 < T when mt>0: valid index
        int colj = cols[pos];

        int mtc = (mt > 64) ? 64 : mt;
        for (int j0 = 0; j0 < mtc; j0 += 8) {
            int nb2 = mtc - j0; if (nb2 > 8) nb2 = 8;
#pragma unroll
            for (int k = 0; k < 8; k++) {
                if (k < nb2) {
                    int c = __shfl(colj, j0 + k, 64);
                    const float4* gp = xb + (size_t)c * 64 + lane;
                    __builtin_amdgcn_global_load_lds(
                        (const __attribute__((address_space(1))) void*)gp,
                        (__attribute__((address_space(3))) void*)(&lds[wave][k][0]),
                        16, 0, 0);
                }
            }
            __builtin_amdgcn_s_waitcnt(0);   // drain the async row fetches
#pragma unroll
            for (int k = 0; k < 8; k++) {
                if (k < nb2) {
                    int rk = __shfl(rowj, j0 + k, 64);   // wave-uniform row id
                    float4 v = lds[wave][k][lane];
                    float w0 = (rk == 0) ? 1.0f : 0.0f;
                    float w1 = (rk == 1) ? 1.0f : 0.0f;
                    float w2 = (rk == 2) ? 1.0f : 0.0f;
                    float w3 = (rk == 3) ? 1.0f : 0.0f;
                    acc0.x = fmaf(v.x, w0, acc0.x); acc0.y = fmaf(v.y, w0, acc0.y);
                    acc0.z = fmaf(v.z, w0, acc0.z); acc0.w = fmaf(v.w, w0, acc0.w);
                    acc1.x = fmaf(v.x, w1, acc1.x); acc1.y = fmaf(v.y, w1, acc1.y);
                    acc1.z = fmaf(v.z, w1, acc1.z); acc1.w = fmaf(v.w, w1, acc1.w);
                    acc2.x = fmaf(v.x, w2, acc2.x); acc2.y = fmaf(v.y, w2, acc2.y);
                    acc2.z = fmaf(v.z, w2, acc2.z); acc2.w = fmaf(v.w, w2, acc2.w);
                    acc3.x = fmaf(v.x, w3, acc3.x); acc3.y = fmaf(v.y, w3, acc3.y);
                    acc3.z = fmaf(v.z, w3, acc3.z); acc3.w = fmaf(v.w, w3, acc3.w);
                }
            }
        }
        if (mt > 64) {   // Poisson(16) tail past 64: astronomically rare
            for (int jq = 64; jq < mt; jq++) {
                int rk = (jq >= c1) + (jq >= c2) + (jq >= c3);
                int pq = ((rk == 0) ? s0 : (rk == 1) ? (s1 - c1)
                        : (rk == 2) ? (s2 - c2) : (s3 - c3)) + jq;
                float4 v = xb[(size_t)cols[pq] * 64 + lane];
                float w0 = (rk == 0) ? 1.0f : 0.0f;
                float w1 = (rk == 1) ? 1.0f : 0.0f;
                float w2 = (rk == 2) ? 1.0f : 0.0f;
                float w3 = (rk == 3) ? 1.0f : 0.0f;
                acc0.x = fmaf(v.x, w0, acc0.x); acc0.y = fmaf(v.y, w0, acc0.y);
                acc0.z = fmaf(v.z, w0, acc0.z); acc0.w = fmaf(v.w, w0, acc0.w);
                acc1.x = fmaf(v.x, w1, acc1.x); acc1.y = fmaf(v.y, w1, acc1.y);
                acc1.z = fmaf(v.z, w1, acc1.z); acc1.w = fmaf(v.w, w1, acc1.w);
                acc2.x = fmaf(v.x, w2, acc2.x); acc2.y = fmaf(v.y, w2, acc2.y);
                acc2.z = fmaf(v.z, w2, acc2.z); acc2.w = fmaf(v.w, w2, acc2.w);
                acc3.x = fmaf(v.x, w3, acc3.x); acc3.y = fmaf(v.y, w3, acc3.y);
                acc3.z = fmaf(v.z, w3, acc3.z); acc3.w = fmaf(v.w, w3, acc3.w);
            }
        }
    }

#define FIN(RR, ACCR)                                                   \
    {                                                                   \
        int i = i0 + (RR);                                              \
        float cnt = fmaxf((float)(__shfl(bnd, (RR) * NB + NB, 64) -     \
                                  __shfl(bnd, (RR) * NB, 64)), 1.0f);   \
        float4 xi = xb[(size_t)i * 64 + lane];                          \
        float dx = xi.x - ACCR.x / cnt;                                 \
        float dy = xi.y - ACCR.y / cnt;                                 \
        float dz = xi.z - ACCR.z / cnt;                                 \
        float dw = xi.w - ACCR.w / cnt;                                 \
        float ss = dx * dx + dy * dy + dz * dz + dw * dw;               \
        _Pragma("unroll")                                               \
        for (int off = 32; off > 0; off >>= 1) ss += __shfl_xor(ss, off, 64); \
        if (lane == 0) fvar[i] = sqrtf(ss);                             \
    }

    FIN(0, acc0);
    FIN(1, acc1);
    FIN(2, acc2);
    FIN(3, acc3);
#undef FIN
}

// ---------------- K5b: maxima reduction (deg, dens, fvar) ----------------
__global__ void __launch_bounds__(256) k_scal(
    const int* __restrict__ rp4, const int* __restrict__ dens,
    const float* __restrict__ fvar, int* __restrict__ scal, int N) {
    __shared__ int sd[4], sn[4];
    __shared__ float sf[4];
    int t = threadIdx.x;
    int g = blockIdx.x * 256 + t;
    int stride = 256 * gridDim.x;
    int md = 0, mn = 0;
    float mf = 0.f;
    for (int i = g; i < N; i += stride) {
        md = max(md, rp4[(i + 1) * NB] - rp4[i * NB]);
        mn = max(mn, dens[i]);
        mf = fmaxf(mf, fvar[i]);
    }
#pragma unroll
    for (int off = 32; off > 0; off >>= 1) {
        md = max(md, __shfl_xor(md, off, 64));
        mn = max(mn, __shfl_xor(mn, off, 64));
        mf = fmaxf(mf, __shfl_xor(mf, off, 64));
    }
    int w = t >> 6, l = t & 63;
    if (l == 0) { sd[w] = md; sn[w] = mn; sf[w] = mf; }
    __syncthreads();
    if (t == 0) {
#pragma unroll
        for (int k = 1; k < 4; k++) {
            md = max(md, sd[k]);
            mn = max(mn, sn[k]);
            mf = fmaxf(mf, sf[k]);
        }
        atomicMax(&scal[0], md);
        atomicMax(&scal[1], mn);
        atomicMax(&scal[2], __float_as_int(mf));   // nonneg float: int-max ok
    }
}

// ---------------- K6: tiny MLP ----------------
__global__ void __launch_bounds__(256) k_mlp(
    const float* __restrict__ w1, const float* __restrict__ b1,
    const float* __restrict__ w2, const float* __restrict__ b2,
    const int* __restrict__ rp4, const int* __restrict__ dens,
    const float* __restrict__ fvar, const int* __restrict__ scal,
    float* __restrict__ out, int N) {
    __shared__ float sh_h[HH];
    int j = threadIdx.x;
    float wv[HH];
#pragma unroll
    for (int l = 0; l < HH; l++) wv[l] = w2[l * H + j];
    float bj = b2[j];
    float maxdeg  = (float)scal[0] + EPSF;
    float maxdens = (float)(scal[1] - 1) + EPSF;
    float maxfv   = __int_as_float(scal[2]) + EPSF;
    float w1a = 0.f, w1b = 0.f, w1c = 0.f, b1j = 0.f;
    if (j < HH) { w1a = w1[j]; w1b = w1[HH + j]; w1c = w1[2 * HH + j]; b1j = b1[j]; }
    for (int i = blockIdx.x; i < N; i += gridDim.x) {
        float f0 = (float)(rp4[(i + 1) * NB] - rp4[i * NB]) / maxdeg;
        float f1 = (float)(dens[i] - 1) / maxdens;
        float f2 = fvar[i] / maxfv;
        if (j < HH) {
            float h = f0 * w1a + f1 * w1b + f2 * w1c + b1j;
            sh_h[j] = fmaxf(h, 0.0f);
        }
        __syncthreads();
        float acc = bj;
#pragma unroll
        for (int l = 0; l < HH; l++) acc = fmaf(sh_h[l], wv[l], acc);
        out[(size_t)i * H + j] = acc;
        __syncthreads();
    }
}

extern "C" void kernel_launch(void* const* d_in, const int* in_sizes, int n_in,
                              void* d_out, int out_size, void* d_ws, size_t ws_size,
                              hipStream_t stream) {
    const float* x      = (const float*)d_in[0];
    const int*   ei     = (const int*)d_in[1];
    const float* coords = (const float*)d_in[2];
    const float* w1     = (const float*)d_in[3];
    const float* b1     = (const float*)d_in[4];
    const float* w2     = (const float*)d_in[5];
    const float* b2     = (const float*)d_in[6];
    float* out = (float*)d_out;

    const int N = in_sizes[2] / 2;   // 16384
    const int E = in_sizes[1] / 2;   // 524288
    const int M = N * NB;            // 131072
    const int NBLK = M / 1024;       // 128 scan blocks
    const int EB = (E + 255) / 256;  // 2048 edge blocks
    const int CB = N / 256;          // 64 coord blocks
    const int* row = ei;
    const int* col = ei + E;

    // workspace layout (int32 elements; int4/float4 arrays 16B-aligned)
    int* ws        = (int*)d_ws;
    int* scal      = ws;                       // [4]     zeroed
    int* deg4      = ws + 4;                   // [M]     zeroed  (16B-aligned)
    int* cellcnt   = ws + 4 + M;               // [404]   zeroed  (400 used)
    int* rp4       = ws + 408 + M;             // [M+4]           (16B-aligned)
    int* cur4      = rp4 + M + 4;              // [M]             (16B-aligned)
    int* cellstart = cur4 + M;                 // [404]   (401 used)
    int* cellcur   = cellstart + 404;          // [400]
    int* dens_cnt  = cellcur + 400;            // [N]
    float* fvarp   = (float*)(dens_cnt + N);   // [N]
    int* bsum      = dens_cnt + 2 * N;         // [128]
    int* boff      = bsum + 128;               // [128] (unused, kept for layout)
    int* cols      = boff + 128;               // [E]
    float4* pts    = (float4*)(cols + E);      // [N]  (16B-aligned)

    hipMemsetAsync(ws, 0, (size_t)(408 + M) * sizeof(int), stream);

    k_degcell<<<EB + CB, 256, 0, stream>>>(row, col, deg4, coords, cellcnt, E, EB, N);
    k_bsum<<<NBLK, 256, 0, stream>>>(deg4, bsum);
    k_scatcell<<<NBLK + 1, 512, 0, stream>>>(deg4, bsum, rp4, cur4, M,
                                             cellcnt, cellstart, cellcur);
    k_fillcell<<<EB + CB, 256, 0, stream>>>(row, col, cur4, cols,
                                            coords, cellcur, pts, E, EB, N);

    k_dgrid<<<N / 4, 256, 0, stream>>>(pts, cellstart, dens_cnt, N);

    k_fvar<<<N / (4 * RPW), 256, 0, stream>>>(x, rp4, cols, fvarp, N);

    k_scal<<<64, 256, 0, stream>>>(rp4, dens_cnt, fvarp, scal, N);

    k_mlp<<<1024, 256, 0, stream>>>(w1, b1, w2, b2, rp4, dens_cnt, fvarp, scal,
                                    out, N);
}

// Round 9
// 246.615 us; speedup vs baseline: 1.3372x; 1.0366x over previous
//
#include <hip/hip_runtime.h>
#include <math.h>

#define R2 2500.0f
#define EPSF 1e-8f

constexpr int H   = 256;   // feature dim (fixed by problem)
constexpr int HH  = 128;   // hidden dim
constexpr int NB  = 8;     // col-buckets per row (bucket = col>>11 -> 2MB of x)
constexpr int BSH = 11;    // bucket shift
constexpr int RPW = 4;     // rows per wave in k_fvar

// ---------------- K1f: degree count + cell count (fused) ----------------
__global__ void __launch_bounds__(256) k_degcell(
    const int* __restrict__ row, const int* __restrict__ col,
    int* __restrict__ deg4, const float* __restrict__ coords,
    int* __restrict__ cellcnt, int E, int EB, int N) {
    if ((int)blockIdx.x < EB) {
        int e = blockIdx.x * 256 + threadIdx.x;
        if (e < E) atomicAdd(&deg4[row[e] * NB + (col[e] >> BSH)], 1);
    } else {
        int t = ((int)blockIdx.x - EB) * 256 + threadIdx.x;
        if (t < N) {
            float2 c = ((const float2*)coords)[t];
            int cx = (int)(c.x * 0.02f); if (cx > 19) cx = 19;
            int cy = (int)(c.y * 0.02f); if (cy > 19) cy = 19;
            atomicAdd(&cellcnt[cy * 20 + cx], 1);
        }
    }
}

// ---------------- K2a: per-block sums over M (128 blocks) ----------------
__global__ void __launch_bounds__(256) k_bsum(const int* __restrict__ deg4,
                                              int* __restrict__ bsum) {
    int t = threadIdx.x;
    int4 v = ((const int4*)deg4)[blockIdx.x * 256 + t];
    int sum = v.x + v.y + v.z + v.w;
#pragma unroll
    for (int off = 32; off > 0; off >>= 1) sum += __shfl_xor(sum, off, 64);
    __shared__ int sw[4];
    if ((t & 63) == 0) sw[t >> 6] = sum;
    __syncthreads();
    if (t == 0) bsum[blockIdx.x] = sw[0] + sw[1] + sw[2] + sw[3];
}

// ---------------- K2f: scat (with internal bsum prefix) + cellscan --------
__global__ void __launch_bounds__(512) k_scatcell(
    const int* __restrict__ deg4, const int* __restrict__ bsum,
    int* __restrict__ rp4, int* __restrict__ cur4, int M,
    const int* __restrict__ cellcnt, int* __restrict__ cellstart,
    int* __restrict__ cellcur) {
    __shared__ int s[512];
    int t = threadIdx.x;
    int blk = blockIdx.x;
    if (blk < gridDim.x - 1) {
        s[t] = (t < 128) ? bsum[t] : 0;
        __syncthreads();
        for (int off = 1; off < 128; off <<= 1) {
            int v = (t < 128) ? s[t] : 0;
            int add = (t >= off && t < 128) ? s[t - off] : 0;
            __syncthreads();
            if (t < 128) s[t] = v + add;
            __syncthreads();
        }
        int boff = (blk > 0) ? s[blk - 1] : 0;
        if (t < 256) {
            int lane = t & 63, w = t >> 6;
            int4 v = ((const int4*)deg4)[blk * 256 + t];
            int tsum = v.x + v.y + v.z + v.w;
            int incl = tsum;
#pragma unroll
            for (int off = 1; off < 64; off <<= 1) {
                int n = __shfl_up(incl, off, 64);
                if (lane >= off) incl += n;
            }
            __shared__ int wsum[4];
            if (lane == 63) wsum[w] = incl;
            __syncthreads();
            int woff = 0;
#pragma unroll
            for (int k = 0; k < 4; k++) woff += (k < w) ? wsum[k] : 0;
            int excl = boff + woff + (incl - tsum);
            int4 r;
            r.x = excl;
            r.y = excl + v.x;
            r.z = excl + v.x + v.y;
            r.w = excl + v.x + v.y + v.z;
            ((int4*)rp4)[blk * 256 + t]  = r;
            ((int4*)cur4)[blk * 256 + t] = r;
            if (blk == 127 && t == 255) rp4[M] = excl + tsum;
        }
    } else {
        s[t] = (t < 400) ? cellcnt[t] : 0;
        __syncthreads();
        for (int off = 1; off < 512; off <<= 1) {
            int v = s[t];
            int add = (t >= off) ? s[t - off] : 0;
            __syncthreads();
            s[t] = v + add;
            __syncthreads();
        }
        if (t < 400) {
            int excl = (t > 0) ? s[t - 1] : 0;
            cellstart[t] = excl;
            cellcur[t]   = excl;
        }
        if (t == 400) cellstart[400] = s[399];
    }
}

// ---------------- K3f: CSR fill + cell fill (fused) ----------------
__global__ void __launch_bounds__(256) k_fillcell(
    const int* __restrict__ row, const int* __restrict__ col,
    int* __restrict__ cur4, int* __restrict__ cols,
    const float* __restrict__ coords, int* __restrict__ cellcur,
    float4* __restrict__ pts, int E, int EB, int N) {
    if ((int)blockIdx.x < EB) {
        int e = blockIdx.x * 256 + threadIdx.x;
        if (e < E) {
            int r = row[e], c = col[e];
            int p = atomicAdd(&cur4[r * NB + (c >> BSH)], 1);
            cols[p] = c;
        }
    } else {
        int t = ((int)blockIdx.x - EB) * 256 + threadIdx.x;
        if (t < N) {
            float2 c = ((const float2*)coords)[t];
            int cx = (int)(c.x * 0.02f); if (cx > 19) cx = 19;
            int cy = (int)(c.y * 0.02f); if (cy > 19) cy = 19;
            int p = atomicAdd(&cellcur[cy * 20 + cx], 1);
            pts[p] = make_float4(c.x, c.y, c.x * c.x + c.y * c.y, __int_as_float(t));
        }
    }
}

// ---------------- K4: density, one wave per point (R6-proven) ----------------
__global__ void __launch_bounds__(256) k_dgrid(
    const float4* __restrict__ pts, const int* __restrict__ cellstart,
    int* __restrict__ dens, int N) {
    int wave = threadIdx.x >> 6;
    int lane = threadIdx.x & 63;
    int t = blockIdx.x * 4 + wave;
    float4 p = pts[t];
    int cx = (int)(p.x * 0.02f); if (cx > 19) cx = 19;
    int cy = (int)(p.y * 0.02f); if (cy > 19) cy = 19;
    int x0 = cx - 2; if (x0 < 0) x0 = 0;
    int x1 = cx + 2; if (x1 > 19) x1 = 19;
    int y0 = cy - 2; if (y0 < 0) y0 = 0;
    int y1 = cy + 2; if (y1 > 19) y1 = 19;
    int cnt = 0;
    for (int yy = y0; yy <= y1; yy++) {
        int rowb = yy * 20;
        int s = cellstart[rowb + x0];
        int e = cellstart[rowb + x1 + 1];
        for (int q = s + lane; q < e; q += 64) {
            float4 pq = pts[q];
            float dot = p.x * pq.x + p.y * pq.y;
            float d2 = (p.z + pq.z) - 2.0f * dot;
            cnt += (d2 <= R2) ? 1 : 0;
        }
    }
#pragma unroll
    for (int off = 32; off > 0; off >>= 1) cnt += __shfl_xor(cnt, off, 64);
    if (lane == 0) dens[__float_as_int(p.w)] = cnt;
}

// ---------------- K5: fvar — bucket sweep, DIRECT VGPR gather -------------
// Hypothesis from R1/R6/R8 invariant (537MB always ~56us = 16B/cy/CU = 1
// lane/cy): global_load_lds serializes lane-requests at the TA. Bypass it:
// plain global_load_dwordx4 into NAMED float4 scalars (no arrays -> no R7
// scratch demotion), 8 independent loads per batch in one straight-line
// block, accumulated with exact *1/*0 weights (slots past m are lane-clamped
// dup indices = L1 hits). Compiler emits progressive vmcnt(N) waits.
// Bucket sweep / RPW=4 / 1024-block co-residency unchanged (FETCH 75MB win).
__global__ void __launch_bounds__(256, 4) k_fvar(
    const float* __restrict__ x, const int* __restrict__ rp4,
    const int* __restrict__ cols, float* __restrict__ fvar, int N) {
    int wave = threadIdx.x >> 6;
    int lane = threadIdx.x & 63;
    int i0 = (blockIdx.x * 4 + wave) * RPW;
    const float4* xb = (const float4*)x;   // 64 float4 per row

    // 33 segment boundaries (rows i0..i0+3 x 8 buckets) in lanes 0..32
    int bnd = rp4[i0 * NB + (lane < 32 ? lane : 32)];

    float4 acc0 = make_float4(0.f, 0.f, 0.f, 0.f);
    float4 acc1 = make_float4(0.f, 0.f, 0.f, 0.f);
    float4 acc2 = make_float4(0.f, 0.f, 0.f, 0.f);
    float4 acc3 = make_float4(0.f, 0.f, 0.f, 0.f);

    for (int b = 0; b < NB; b++) {
#pragma unroll
        for (int r = 0; r < RPW; r++) {
            float4& a = (r == 0) ? acc0 : (r == 1) ? acc1 : (r == 2) ? acc2 : acc3;
            int s = __shfl(bnd, r * NB + b, 64);
            int e = __shfl(bnd, r * NB + b + 1, 64);
            for (int p0 = s; p0 < e; p0 += 64) {
                int m = e - p0; if (m > 64) m = 64;
                int idx = cols[p0 + (lane < m ? lane : m - 1)];  // lane-clamped
                for (int j = 0; j < m; j += 8) {
                    int nb2 = m - j; if (nb2 > 8) nb2 = 8;
                    // 8 unconditional loads (clamped dups = L1 hits), named regs
                    float4 g0 = xb[(size_t)__shfl(idx, j + 0, 64) * 64 + lane];
                    float4 g1 = xb[(size_t)__shfl(idx, j + 1, 64) * 64 + lane];
                    float4 g2 = xb[(size_t)__shfl(idx, j + 2, 64) * 64 + lane];
                    float4 g3 = xb[(size_t)__shfl(idx, j + 3, 64) * 64 + lane];
                    float4 g4 = xb[(size_t)__shfl(idx, j + 4, 64) * 64 + lane];
                    float4 g5 = xb[(size_t)__shfl(idx, j + 5, 64) * 64 + lane];
                    float4 g6 = xb[(size_t)__shfl(idx, j + 6, 64) * 64 + lane];
                    float4 g7 = xb[(size_t)__shfl(idx, j + 7, 64) * 64 + lane];
                    float w0 = (1 < nb2 + 1) ? 1.0f : 0.0f;   // k=0 always valid
                    float w1 = (1 < nb2) ? 1.0f : 0.0f;
                    float w2 = (2 < nb2) ? 1.0f : 0.0f;
                    float w3 = (3 < nb2) ? 1.0f : 0.0f;
                    float w4 = (4 < nb2) ? 1.0f : 0.0f;
                    float w5 = (5 < nb2) ? 1.0f : 0.0f;
                    float w6 = (6 < nb2) ? 1.0f : 0.0f;
                    float w7 = (7 < nb2) ? 1.0f : 0.0f;
                    a.x = fmaf(g0.x, w0, a.x); a.y = fmaf(g0.y, w0, a.y);
                    a.z = fmaf(g0.z, w0, a.z); a.w = fmaf(g0.w, w0, a.w);
                    a.x = fmaf(g1.x, w1, a.x); a.y = fmaf(g1.y, w1, a.y);
                    a.z = fmaf(g1.z, w1, a.z); a.w = fmaf(g1.w, w1, a.w);
                    a.x = fmaf(g2.x, w2, a.x); a.y = fmaf(g2.y, w2, a.y);
                    a.z = fmaf(g2.z, w2, a.z); a.w = fmaf(g2.w, w2, a.w);
                    a.x = fmaf(g3.x, w3, a.x); a.y = fmaf(g3.y, w3, a.y);
                    a.z = fmaf(g3.z, w3, a.z); a.w = fmaf(g3.w, w3, a.w);
                    a.x = fmaf(g4.x, w4, a.x); a.y = fmaf(g4.y, w4, a.y);
                    a.z = fmaf(g4.z, w4, a.z); a.w = fmaf(g4.w, w4, a.w);
                    a.x = fmaf(g5.x, w5, a.x); a.y = fmaf(g5.y, w5, a.y);
                    a.z = fmaf(g5.z, w5, a.z); a.w = fmaf(g5.w, w5, a.w);
                    a.x = fmaf(g6.x, w6, a.x); a.y = fmaf(g6.y, w6, a.y);
                    a.z = fmaf(g6.z, w6, a.z); a.w = fmaf(g6.w, w6, a.w);
                    a.x = fmaf(g7.x, w7, a.x); a.y = fmaf(g7.y, w7, a.y);
                    a.z = fmaf(g7.z, w7, a.z); a.w = fmaf(g7.w, w7, a.w);
                }
            }
        }
    }

#define FIN(RR, ACCR)                                                   \
    {                                                                   \
        int i = i0 + (RR);                                              \
        float cnt = fmaxf((float)(__shfl(bnd, (RR) * NB + NB, 64) -     \
                                  __shfl(bnd, (RR) * NB, 64)), 1.0f);   \
        float4 xi = xb[(size_t)i * 64 + lane];                          \
        float dx = xi.x - ACCR.x / cnt;                                 \
        float dy = xi.y - ACCR.y / cnt;                                 \
        float dz = xi.z - ACCR.z / cnt;                                 \
        float dw = xi.w - ACCR.w / cnt;                                 \
        float ss = dx * dx + dy * dy + dz * dz + dw * dw;               \
        _Pragma("unroll")                                               \
        for (int off = 32; off > 0; off >>= 1) ss += __shfl_xor(ss, off, 64); \
        if (lane == 0) fvar[i] = sqrtf(ss);                             \
    }

    FIN(0, acc0);
    FIN(1, acc1);
    FIN(2, acc2);
    FIN(3, acc3);
#undef FIN
}

// ---------------- K5b: maxima reduction (deg, dens, fvar) ----------------
__global__ void __launch_bounds__(256) k_scal(
    const int* __restrict__ rp4, const int* __restrict__ dens,
    const float* __restrict__ fvar, int* __restrict__ scal, int N) {
    __shared__ int sd[4], sn[4];
    __shared__ float sf[4];
    int t = threadIdx.x;
    int g = blockIdx.x * 256 + t;
    int stride = 256 * gridDim.x;
    int md = 0, mn = 0;
    float mf = 0.f;
    for (int i = g; i < N; i += stride) {
        md = max(md, rp4[(i + 1) * NB] - rp4[i * NB]);
        mn = max(mn, dens[i]);
        mf = fmaxf(mf, fvar[i]);
    }
#pragma unroll
    for (int off = 32; off > 0; off >>= 1) {
        md = max(md, __shfl_xor(md, off, 64));
        mn = max(mn, __shfl_xor(mn, off, 64));
        mf = fmaxf(mf, __shfl_xor(mf, off, 64));
    }
    int w = t >> 6, l = t & 63;
    if (l == 0) { sd[w] = md; sn[w] = mn; sf[w] = mf; }
    __syncthreads();
    if (t == 0) {
#pragma unroll
        for (int k = 1; k < 4; k++) {
            md = max(md, sd[k]);
            mn = max(mn, sn[k]);
            mf = fmaxf(mf, sf[k]);
        }
        atomicMax(&scal[0], md);
        atomicMax(&scal[1], mn);
        atomicMax(&scal[2], __float_as_int(mf));   // nonneg float: int-max ok
    }
}

// ---------------- K6: tiny MLP ----------------
__global__ void __launch_bounds__(256) k_mlp(
    const float* __restrict__ w1, const float* __restrict__ b1,
    const float* __restrict__ w2, const float* __restrict__ b2,
    const int* __restrict__ rp4, const int* __restrict__ dens,
    const float* __restrict__ fvar, const int* __restrict__ scal,
    float* __restrict__ out, int N) {
    __shared__ float sh_h[HH];
    int j = threadIdx.x;
    float wv[HH];
#pragma unroll
    for (int l = 0; l < HH; l++) wv[l] = w2[l * H + j];
    float bj = b2[j];
    float maxdeg  = (float)scal[0] + EPSF;
    float maxdens = (float)(scal[1] - 1) + EPSF;
    float maxfv   = __int_as_float(scal[2]) + EPSF;
    float w1a = 0.f, w1b = 0.f, w1c = 0.f, b1j = 0.f;
    if (j < HH) { w1a = w1[j]; w1b = w1[HH + j]; w1c = w1[2 * HH + j]; b1j = b1[j]; }
    for (int i = blockIdx.x; i < N; i += gridDim.x) {
        float f0 = (float)(rp4[(i + 1) * NB] - rp4[i * NB]) / maxdeg;
        float f1 = (float)(dens[i] - 1) / maxdens;
        float f2 = fvar[i] / maxfv;
        if (j < HH) {
            float h = f0 * w1a + f1 * w1b + f2 * w1c + b1j;
            sh_h[j] = fmaxf(h, 0.0f);
        }
        __syncthreads();
        float acc = bj;
#pragma unroll
        for (int l = 0; l < HH; l++) acc = fmaf(sh_h[l], wv[l], acc);
        out[(size_t)i * H + j] = acc;
        __syncthreads();
    }
}

extern "C" void kernel_launch(void* const* d_in, const int* in_sizes, int n_in,
                              void* d_out, int out_size, void* d_ws, size_t ws_size,
                              hipStream_t stream) {
    const float* x      = (const float*)d_in[0];
    const int*   ei     = (const int*)d_in[1];
    const float* coords = (const float*)d_in[2];
    const float* w1     = (const float*)d_in[3];
    const float* b1     = (const float*)d_in[4];
    const float* w2     = (const float*)d_in[5];
    const float* b2     = (const float*)d_in[6];
    float* out = (float*)d_out;

    const int N = in_sizes[2] / 2;   // 16384
    const int E = in_sizes[1] / 2;   // 524288
    const int M = N * NB;            // 131072
    const int NBLK = M / 1024;       // 128 scan blocks
    const int EB = (E + 255) / 256;  // 2048 edge blocks
    const int CB = N / 256;          // 64 coord blocks
    const int* row = ei;
    const int* col = ei + E;

    // workspace layout (int32 elements; int4/float4 arrays 16B-aligned)
    int* ws        = (int*)d_ws;
    int* scal      = ws;                       // [4]     zeroed
    int* deg4      = ws + 4;                   // [M]     zeroed  (16B-aligned)
    int* cellcnt   = ws + 4 + M;               // [404]   zeroed  (400 used)
    int* rp4       = ws + 408 + M;             // [M+4]           (16B-aligned)
    int* cur4      = rp4 + M + 4;              // [M]             (16B-aligned)
    int* cellstart = cur4 + M;                 // [404]   (401 used)
    int* cellcur   = cellstart + 404;          // [400]
    int* dens_cnt  = cellcur + 400;            // [N]
    float* fvarp   = (float*)(dens_cnt + N);   // [N]
    int* bsum      = dens_cnt + 2 * N;         // [128]
    int* boff      = bsum + 128;               // [128] (unused, kept for layout)
    int* cols      = boff + 128;               // [E]
    float4* pts    = (float4*)(cols + E);      // [N]  (16B-aligned)

    hipMemsetAsync(ws, 0, (size_t)(408 + M) * sizeof(int), stream);

    k_degcell<<<EB + CB, 256, 0, stream>>>(row, col, deg4, coords, cellcnt, E, EB, N);
    k_bsum<<<NBLK, 256, 0, stream>>>(deg4, bsum);
    k_scatcell<<<NBLK + 1, 512, 0, stream>>>(deg4, bsum, rp4, cur4, M,
                                             cellcnt, cellstart, cellcur);
    k_fillcell<<<EB + CB, 256, 0, stream>>>(row, col, cur4, cols,
                                            coords, cellcur, pts, E, EB, N);

    k_dgrid<<<N / 4, 256, 0, stream>>>(pts, cellstart, dens_cnt, N);

    k_fvar<<<N / (4 * RPW), 256, 0, stream>>>(x, rp4, cols, fvarp, N);

    k_scal<<<64, 256, 0, stream>>>(rp4, dens_cnt, fvarp, scal, N);

    k_mlp<<<1024, 256, 0, stream>>>(w1, b1, w2, b2, rp4, dens_cnt, fvarp, scal,
                                    out, N);
}